// Round 9
// baseline (343.266 us; speedup 1.0000x reference)
//
#include <hip/hip_runtime.h>
#include <math.h>

#define BATCH 4096
#define SEQ_T 512
#define ISZ   4
#define HID   64
#define OSZ   40
#define RPB   32     // two 16-col MFMA tiles per block -> 128 blocks; 2 chains per wave (ILP)

typedef __attribute__((ext_vector_type(8))) _Float16     half8;
typedef __attribute__((ext_vector_type(2))) _Float16     half2v;
typedef __attribute__((ext_vector_type(4))) float        float4v;
typedef __attribute__((ext_vector_type(2))) unsigned int uint2v;

static __device__ __forceinline__ half2v pk_f16(float a, float b) {
    return __builtin_bit_cast(half2v, __builtin_amdgcn_cvt_pkrtz(a, b)); // v_cvt_pkrtz_f16_f32
}
// tanh(x) = 1 - 2/(exp(2x)+1); saturates to +/-1, NaN-free
static __device__ __forceinline__ float fast_tanh(float x) {
    float e = __expf(2.0f * x);
    return 1.0f - 2.0f * __builtin_amdgcn_rcpf(e + 1.0f);
}

__global__ __launch_bounds__(256, 1)
void rnn_dual_kernel(const float* __restrict__ x,
                     const float* __restrict__ W_ih,
                     const float* __restrict__ W_hh,
                     const float* __restrict__ b_ih,
                     const float* __restrict__ b_hh,
                     const float* __restrict__ fc_W,
                     const float* __restrict__ fc_b,
                     float* __restrict__ out)
{
    // Per-tile h terms, B-fragment-native: hterm[tile][buf][term][g][n][j] = h_term[k=8g+j], col n.
    __shared__ __attribute__((aligned(16))) _Float16 hterm[2][2][2][8][16][8];
    __shared__ __attribute__((aligned(16))) float hf[2][16][68];

    const int tid  = threadIdx.x;
    const int wv   = tid >> 6;
    const int lane = tid & 63;
    const int n    = lane & 15;
    const int q    = lane >> 4;
    const int blk0 = blockIdx.x * RPB;

    // h(0) = 0
    {
        unsigned int* p = (unsigned int*)hterm;
        #pragma unroll
        for (int i = tid; i < (int)(sizeof(hterm) / 4); i += 256) p[i] = 0u;
    }

    // ---- static A fragments (shared by both tiles): W_hh row 16wv+n, fp16 2-term split ----
    half8 A10, A11, A20, A21;
    {
        const float* wr = W_hh + (16 * wv + n) * HID;
        #pragma unroll
        for (int j = 0; j < 8; ++j) {
            float f0 = wr[     8 * q + j];
            float f1 = wr[32 + 8 * q + j];
            _Float16 h0 = (_Float16)f0; A10[j] = h0; A20[j] = (_Float16)(f0 - (float)h0);
            _Float16 h1 = (_Float16)f1; A11[j] = h1; A21[j] = (_Float16)(f1 - (float)h1);
        }
    }

    // ---- fp32 x-projection weights + bias for C rows 16wv + 4q + r (shared) ----
    const int r0 = 16 * wv + 4 * q;
    float wih[4][4], bias[4];
    #pragma unroll
    for (int r = 0; r < 4; ++r) {
        bias[r] = b_ih[r0 + r] + b_hh[r0 + r];
        #pragma unroll
        for (int i = 0; i < ISZ; ++i) wih[r][i] = W_ih[(r0 + r) * ISZ + i];
    }

    // ---- per-lane x pipelines, one per tile ----
    const float* xrowA = x + (size_t)(blk0      + n) * SEQ_T * ISZ;
    const float* xrowB = x + (size_t)(blk0 + 16 + n) * SEQ_T * ISZ;
    float4v xcurA = *(const float4v*)(xrowA);
    float4v xnxtA = *(const float4v*)(xrowA + ISZ);
    float4v xcurB = *(const float4v*)(xrowB);
    float4v xnxtB = *(const float4v*)(xrowB + ISZ);

    const int gw = 2 * wv + (q >> 1);
    const int j0 = 4 * (q & 1);

    float hlA0 = 0.f, hlA1 = 0.f, hlA2 = 0.f, hlA3 = 0.f;
    float hlB0 = 0.f, hlB1 = 0.f, hlB2 = 0.f, hlB3 = 0.f;

    __syncthreads();   // zero-init visible

#define MFMA16(A, B, C) __builtin_amdgcn_mfma_f32_16x16x32_f16((A), (B), (C), 0, 0, 0)
// One tile's step body; SUF = A/B, TI = 0/1. Persistent state: xcur##SUF, xnxt##SUF, hl##SUF0..3.
#define TILE_BODY(TI, SUF, RB, WB, T)                                          \
    {                                                                          \
        int tn = (T) + 2; if (tn > SEQ_T - 1) tn = SEQ_T - 1;                  \
        const float4v xf = *(const float4v*)(xrow##SUF + (size_t)tn * ISZ);    \
        half8 B10 = *(const half8*)&hterm[TI][RB][0][    q][n][0];             \
        half8 B11 = *(const half8*)&hterm[TI][RB][0][4 + q][n][0];             \
        half8 B20 = *(const half8*)&hterm[TI][RB][1][    q][n][0];             \
        half8 B21 = *(const half8*)&hterm[TI][RB][1][4 + q][n][0];             \
        float p0 = bias[0], p1 = bias[1], p2 = bias[2], p3 = bias[3];          \
        _Pragma("unroll")                                                      \
        for (int i = 0; i < ISZ; ++i) {                                        \
            p0 = fmaf(xcur##SUF[i], wih[0][i], p0);                            \
            p1 = fmaf(xcur##SUF[i], wih[1][i], p1);                            \
            p2 = fmaf(xcur##SUF[i], wih[2][i], p2);                            \
            p3 = fmaf(xcur##SUF[i], wih[3][i], p3);                            \
        }                                                                      \
        float4v accA = {p0, p1, p2, p3};                                       \
        float4v accB = {0.f, 0.f, 0.f, 0.f};                                   \
        accA = MFMA16(A10, B10, accA);  accB = MFMA16(A11, B11, accB);         \
        accA = MFMA16(A10, B20, accA);  accB = MFMA16(A11, B21, accB);         \
        accA = MFMA16(A20, B10, accA);  accB = MFMA16(A21, B11, accB);         \
        hl##SUF##0 = fast_tanh(accA[0] + accB[0]);                             \
        hl##SUF##1 = fast_tanh(accA[1] + accB[1]);                             \
        hl##SUF##2 = fast_tanh(accA[2] + accB[2]);                             \
        hl##SUF##3 = fast_tanh(accA[3] + accB[3]);                             \
        half2v hi01 = pk_f16(hl##SUF##0, hl##SUF##1);                          \
        half2v hi23 = pk_f16(hl##SUF##2, hl##SUF##3);                          \
        float s0 = hl##SUF##0 - (float)hi01[0], s1 = hl##SUF##1 - (float)hi01[1]; \
        float s2 = hl##SUF##2 - (float)hi23[0], s3 = hl##SUF##3 - (float)hi23[1]; \
        half2v lo01 = pk_f16(s0, s1), lo23 = pk_f16(s2, s3);                   \
        uint2v whi = { __builtin_bit_cast(unsigned int, hi01),                 \
                       __builtin_bit_cast(unsigned int, hi23) };               \
        uint2v wlo = { __builtin_bit_cast(unsigned int, lo01),                 \
                       __builtin_bit_cast(unsigned int, lo23) };               \
        *(uint2v*)&hterm[TI][WB][0][gw][n][j0] = whi;                          \
        *(uint2v*)&hterm[TI][WB][1][gw][n][j0] = wlo;                          \
        xcur##SUF = xnxt##SUF; xnxt##SUF = xf;                                 \
    }

#define RNN_STEP(RB, WB, T)                                                    \
    TILE_BODY(0, A, RB, WB, T)                                                 \
    TILE_BODY(1, B, RB, WB, T)                                                 \
    __syncthreads();

    for (int t = 0; t < SEQ_T; t += 2) {
        RNN_STEP(0, 1, t)
        RNN_STEP(1, 0, t + 1)
    }
#undef RNN_STEP
#undef TILE_BODY
#undef MFMA16

    // ---- fc epilogue on fp32 final h ----
    {
        float4v hvA = {hlA0, hlA1, hlA2, hlA3};
        float4v hvB = {hlB0, hlB1, hlB2, hlB3};
        *(float4v*)&hf[0][n][16 * wv + 4 * q] = hvA;
        *(float4v*)&hf[1][n][16 * wv + 4 * q] = hvB;
    }
    __syncthreads();
    for (int it = tid; it < RPB * OSZ; it += 256) {
        const int b  = it / OSZ;           // 0..31
        const int o  = it - b * OSZ;
        const int ti = b >> 4;
        const int bb = b & 15;
        const float* wo = fc_W + o * HID;
        float acc = fc_b[o];
        #pragma unroll
        for (int j = 0; j < HID; ++j)
            acc = fmaf(hf[ti][bb][j], wo[j], acc);
        out[(size_t)(blk0 + b) * OSZ + o] = acc;
    }
}

extern "C" void kernel_launch(void* const* d_in, const int* in_sizes, int n_in,
                              void* d_out, int out_size, void* d_ws, size_t ws_size,
                              hipStream_t stream) {
    const float* x    = (const float*)d_in[0];
    const float* W_ih = (const float*)d_in[1];
    const float* W_hh = (const float*)d_in[2];
    const float* b_ih = (const float*)d_in[3];
    const float* b_hh = (const float*)d_in[4];
    const float* fc_W = (const float*)d_in[5];
    const float* fc_b = (const float*)d_in[6];
    float* out = (float*)d_out;

    rnn_dual_kernel<<<BATCH / RPB, 256, 0, stream>>>(
        x, W_ih, W_hh, b_ih, b_hh, fc_W, fc_b, out);
}

// Round 10
// 301.917 us; speedup vs baseline: 1.1370x; 1.1370x over previous
//
#include <hip/hip_runtime.h>
#include <math.h>

#define BATCH 4096
#define SEQ_T 512
#define ISZ   4
#define HID   64
#define OSZ   40
#define RPB   16   // 16 batch cols per block; 256 blocks (1/CU); 128 threads = 2 waves, M=32 each

typedef __attribute__((ext_vector_type(8))) _Float16     half8;
typedef __attribute__((ext_vector_type(2))) _Float16     half2v;
typedef __attribute__((ext_vector_type(4))) float        float4v;
typedef __attribute__((ext_vector_type(2))) unsigned int uint2v;
typedef __attribute__((ext_vector_type(4))) unsigned int uint4v;

static __device__ __forceinline__ half2v pk_f16(float a, float b) {
    return __builtin_bit_cast(half2v, __builtin_amdgcn_cvt_pkrtz(a, b)); // v_cvt_pkrtz_f16_f32
}
// tanh(x) = 1 - 2/(exp(2x)+1); saturates to +/-1, NaN-free
static __device__ __forceinline__ float fast_tanh(float x) {
    float e = __expf(2.0f * x);
    return 1.0f - 2.0f * __builtin_amdgcn_rcpf(e + 1.0f);
}

__global__ __launch_bounds__(128, 1)
void rnn_w2_kernel(const float* __restrict__ x,
                   const float* __restrict__ W_ih,
                   const float* __restrict__ W_hh,
                   const float* __restrict__ b_ih,
                   const float* __restrict__ b_hh,
                   const float* __restrict__ fc_W,
                   const float* __restrict__ fc_b,
                   float* __restrict__ out)
{
    // h terms, B-fragment-native: hterm[buf][term][g][n][j] = h_term[k=8g+j], batch col n.
    // Reads (both waves): b128 at [term][4c+q][n][0], banks (4n+d)%32 -> 2-way (free).
    // Writes: wave wv, sub-tile s owns rows 32wv+16s+4q+r -> g=4wv+2s+(q>>1), one b64/term.
    __shared__ __attribute__((aligned(16))) _Float16 hterm[2][2][8][16][8];
    __shared__ __attribute__((aligned(16))) float hf[16][68];

    const int tid  = threadIdx.x;
    const int wv   = tid >> 6;      // 0..1
    const int lane = tid & 63;
    const int n    = lane & 15;     // A: row m; B/C/D: batch col n
    const int q    = lane >> 4;
    const int blk0 = blockIdx.x * RPB;
    const int j0   = 4 * (q & 1);

    // h(0) = 0: zero both buffers
    {
        unsigned int* p = (unsigned int*)hterm;
        #pragma unroll
        for (int i = tid; i < (int)(sizeof(hterm) / 4); i += 128) p[i] = 0u;
    }

    // ---- static A fragments: sub-tile s covers W_hh rows 32wv+16s+0..15 ----
    half8 A1c0[2], A1c1[2], A2c0[2], A2c1[2], A3[2];
    #pragma unroll
    for (int s = 0; s < 2; ++s) {
        const int row = 32 * wv + 16 * s + n;
        const float* wr = W_hh + row * HID;
        #pragma unroll
        for (int j = 0; j < 8; ++j) {
            float f0 = wr[     8 * q + j];
            float f1 = wr[32 + 8 * q + j];
            _Float16 h0 = (_Float16)f0; A1c0[s][j] = h0; A2c0[s][j] = (_Float16)(f0 - (float)h0);
            _Float16 h1 = (_Float16)f1; A1c1[s][j] = h1; A2c1[s][j] = (_Float16)(f1 - (float)h1);
        }
        // A3: xproj+bias operand. Pairs with B3 so that A3·B3 = W_ih·x + bias (drops Wlo·xlo ~2^-22).
        float wf0 = W_ih[row * 4 + 0], wf1 = W_ih[row * 4 + 1];
        float wf2 = W_ih[row * 4 + 2], wf3 = W_ih[row * 4 + 3];
        float bs  = b_ih[row] + b_hh[row];
        _Float16 bh = (_Float16)bs;
        _Float16 bl = (_Float16)(bs - (float)bh);
        #pragma unroll
        for (int j = 0; j < 8; ++j) {
            float w = (j&3)==0 ? wf0 : (j&3)==1 ? wf1 : (j&3)==2 ? wf2 : wf3;
            _Float16 whi = (_Float16)w;
            _Float16 wlo = (_Float16)(w - (float)whi);
            _Float16 v = (_Float16)0.0f;
            if (q == 0) v = whi;
            else if (q == 1) v = (j < 4) ? wlo : (j == 4) ? bh : (j == 5) ? bl : (_Float16)0.0f;
            A3[s][j] = v;
        }
    }

    // ---- per-lane x pipeline (fp32 from global, 2-step lookahead) ----
    const float* xrow = x + (size_t)(blk0 + n) * SEQ_T * ISZ;
    float4v xcur = *(const float4v*)(xrow);
    float4v xnxt = *(const float4v*)(xrow + ISZ);

    float hl[2][4] = {{0.f,0.f,0.f,0.f},{0.f,0.f,0.f,0.f}};

    const unsigned int ONE2 = 0x3C003C00u;  // (1.0h, 1.0h)

    __syncthreads();   // zero-init visible

#define MFMA16(A, B, C) __builtin_amdgcn_mfma_f32_16x16x32_f16((A), (B), (C), 0, 0, 0)
#define RNN_STEP(RB, WB, T)                                                    \
    {                                                                          \
        int tn = (T) + 2; if (tn > SEQ_T - 1) tn = SEQ_T - 1;                  \
        const float4v xf = *(const float4v*)(xrow + (size_t)tn * ISZ);         \
        half8 B10 = *(const half8*)&hterm[RB][0][    q][n][0];                 \
        half8 B11 = *(const half8*)&hterm[RB][0][4 + q][n][0];                 \
        half8 B20 = *(const half8*)&hterm[RB][1][    q][n][0];                 \
        half8 B21 = *(const half8*)&hterm[RB][1][4 + q][n][0];                 \
        /* B3: q0=[xhi|xlo], q1=[xhi|1,1,0,0], q2/q3=0 */                      \
        half2v xh01 = pk_f16(xcur[0], xcur[1]), xh23 = pk_f16(xcur[2], xcur[3]); \
        float l0 = xcur[0] - (float)xh01[0], l1 = xcur[1] - (float)xh01[1];    \
        float l2 = xcur[2] - (float)xh23[0], l3 = xcur[3] - (float)xh23[1];    \
        half2v xl01 = pk_f16(l0, l1), xl23 = pk_f16(l2, l3);                   \
        unsigned int uh01 = __builtin_bit_cast(unsigned int, xh01);            \
        unsigned int uh23 = __builtin_bit_cast(unsigned int, xh23);            \
        unsigned int ul01 = __builtin_bit_cast(unsigned int, xl01);            \
        unsigned int ul23 = __builtin_bit_cast(unsigned int, xl23);            \
        uint4v bt = { (q < 2) ? uh01 : 0u,                                     \
                      (q < 2) ? uh23 : 0u,                                     \
                      (q == 0) ? ul01 : (q == 1) ? ONE2 : 0u,                  \
                      (q == 0) ? ul23 : 0u };                                  \
        half8 B3 = __builtin_bit_cast(half8, bt);                              \
        _Pragma("unroll")                                                      \
        for (int s = 0; s < 2; ++s) {                                          \
            float4v accA = {0.f, 0.f, 0.f, 0.f};                               \
            float4v accB = {0.f, 0.f, 0.f, 0.f};                               \
            accB = MFMA16(A3[s],   B3,  accB);                                 \
            accA = MFMA16(A1c0[s], B10, accA);                                 \
            accB = MFMA16(A1c1[s], B11, accB);                                 \
            accA = MFMA16(A1c0[s], B20, accA);                                 \
            accB = MFMA16(A1c1[s], B21, accB);                                 \
            accA = MFMA16(A2c0[s], B10, accA);                                 \
            accB = MFMA16(A2c1[s], B11, accB);                                 \
            hl[s][0] = fast_tanh(accA[0] + accB[0]);                           \
            hl[s][1] = fast_tanh(accA[1] + accB[1]);                           \
            hl[s][2] = fast_tanh(accA[2] + accB[2]);                           \
            hl[s][3] = fast_tanh(accA[3] + accB[3]);                           \
            half2v hi01 = pk_f16(hl[s][0], hl[s][1]);                          \
            half2v hi23 = pk_f16(hl[s][2], hl[s][3]);                          \
            float s0 = hl[s][0] - (float)hi01[0], s1 = hl[s][1] - (float)hi01[1]; \
            float s2 = hl[s][2] - (float)hi23[0], s3 = hl[s][3] - (float)hi23[1]; \
            half2v lo01 = pk_f16(s0, s1), lo23 = pk_f16(s2, s3);               \
            uint2v whi = { __builtin_bit_cast(unsigned int, hi01),             \
                           __builtin_bit_cast(unsigned int, hi23) };           \
            uint2v wlo = { __builtin_bit_cast(unsigned int, lo01),             \
                           __builtin_bit_cast(unsigned int, lo23) };           \
            const int g = 4 * wv + 2 * s + (q >> 1);                           \
            *(uint2v*)&hterm[WB][0][g][n][j0] = whi;                           \
            *(uint2v*)&hterm[WB][1][g][n][j0] = wlo;                           \
        }                                                                      \
        xcur = xnxt; xnxt = xf;                                                \
        __syncthreads();                                                       \
    }

    for (int t = 0; t < SEQ_T; t += 2) {
        RNN_STEP(0, 1, t)
        RNN_STEP(1, 0, t + 1)
    }
#undef RNN_STEP
#undef MFMA16

    // ---- fc epilogue on fp32 final h ----
    #pragma unroll
    for (int s = 0; s < 2; ++s) {
        float4v hv = {hl[s][0], hl[s][1], hl[s][2], hl[s][3]};
        *(float4v*)&hf[n][32 * wv + 16 * s + 4 * q] = hv;
    }
    __syncthreads();
    for (int it = tid; it < RPB * OSZ; it += 128) {
        const int b = it / OSZ;
        const int o = it - b * OSZ;
        const float* wo = fc_W + o * HID;
        float acc = fc_b[o];
        #pragma unroll
        for (int j = 0; j < HID; ++j)
            acc = fmaf(hf[b][j], wo[j], acc);
        out[(size_t)(blk0 + b) * OSZ + o] = acc;
    }
}

extern "C" void kernel_launch(void* const* d_in, const int* in_sizes, int n_in,
                              void* d_out, int out_size, void* d_ws, size_t ws_size,
                              hipStream_t stream) {
    const float* x    = (const float*)d_in[0];
    const float* W_ih = (const float*)d_in[1];
    const float* W_hh = (const float*)d_in[2];
    const float* b_ih = (const float*)d_in[3];
    const float* b_hh = (const float*)d_in[4];
    const float* fc_W = (const float*)d_in[5];
    const float* fc_b = (const float*)d_in[6];
    float* out = (float*)d_out;

    rnn_w2_kernel<<<BATCH / RPB, 128, 0, stream>>>(
        x, W_ih, W_hh, b_ih, b_hh, fc_W, fc_b, out);
}